// Round 1
// baseline (248.410 us; speedup 1.0000x reference)
//
#include <hip/hip_runtime.h>

// 3-layer GCN on MI355X. Key algebraic move: A_hat(xW) == (A_hat x)W, so each
// layer aggregates in whichever feature dim is smaller. CSR-by-dst built on
// device each call (workspace is re-poisoned every replay).

constexpr int NN = 20000;   // nodes
constexpr int NE = 320000;  // edges
constexpr int F0 = 10;      // input feats
constexpr int F1 = 256;     // layer1 out
constexpr int F2 = 128;     // layer2 out
constexpr int MB = 16;      // nodes per block in fused gemm12

// ---------- graph build ----------

__global__ void k_init(float* deg, int* cursor) {
  int i = blockIdx.x * 256 + threadIdx.x;
  if (i < NN) { deg[i] = 1.0f; cursor[i] = 0; }  // self-loop counts as 1
}

__global__ void k_count(const int* __restrict__ dst, float* deg) {
  int e = blockIdx.x * 256 + threadIdx.x;
  if (e < NE) atomicAdd(&deg[dst[e]], 1.0f);
}

// single block: exclusive-prefix of in-edge counts (deg-1) -> rowp, and deg -> rsqrt(deg)
__global__ void k_scan(float* deg, int* rowp) {
  __shared__ int part[1024];
  const int t = threadIdx.x;
  const int CH = (NN + 1023) / 1024;  // 20
  const int base = t * CH;
  const int end = min(base + CH, NN);
  int s = 0;
  for (int i = base; i < end; ++i) s += (int)deg[i] - 1;
  part[t] = s;
  __syncthreads();
  for (int off = 1; off < 1024; off <<= 1) {
    int v = (t >= off) ? part[t - off] : 0;
    __syncthreads();
    part[t] += v;
    __syncthreads();
  }
  int run = part[t] - s;  // exclusive prefix
  for (int i = base; i < end; ++i) {
    float d = deg[i];
    rowp[i] = run;
    run += (int)d - 1;
    deg[i] = rsqrtf(d);  // deg >= 1 always
  }
  if (t == 0) rowp[NN] = NE;
}

__global__ void k_fill(const int* __restrict__ src, const int* __restrict__ dst,
                       const float* __restrict__ dinv, const int* __restrict__ rowp,
                       int* cursor, int* __restrict__ col, float* __restrict__ enorm) {
  int e = blockIdx.x * 256 + threadIdx.x;
  if (e < NE) {
    int d = dst[e], s = src[e];
    int pos = rowp[d] + atomicAdd(&cursor[d], 1);
    col[pos] = s;
    enorm[pos] = dinv[s] * dinv[d];
  }
}

// ---------- layer 1: a1 = A_hat x  (10 feats), 16 threads per node ----------

__global__ void k_aggx(const float* __restrict__ x, const float* __restrict__ dinv,
                       const int* __restrict__ rowp, const int* __restrict__ col,
                       const float* __restrict__ enorm, float* __restrict__ a1) {
  int gid = blockIdx.x * 256 + threadIdx.x;
  int n = gid >> 4;
  int f = gid & 15;
  if (n >= NN || f >= F0) return;
  int jb = rowp[n], je = rowp[n + 1];
  float acc = 0.f;
  for (int j = jb; j < je; ++j) {
    int s = col[j];
    float w = enorm[j];
    acc += x[s * F0 + f] * w;
  }
  float di = dinv[n];
  acc += x[n * F0 + f] * di * di;
  a1[n * F0 + f] = acc;
}

// ---------- fused: h1 = relu(a1 W1 + b1) in LDS; t2 = h1 W2 ----------

__global__ __launch_bounds__(256) void k_gemm12(
    const float* __restrict__ a1, const float* __restrict__ W1,
    const float* __restrict__ b1, const float* __restrict__ W2,
    float* __restrict__ t2) {
  __shared__ float alds[MB * F0];  // 640 B
  __shared__ float h1T[F1][MB];    // 16 KB, transposed: h1T[k][m]
  const int tid = threadIdx.x;
  const int n0 = blockIdx.x * MB;
  if (tid < MB * F0) alds[tid] = a1[n0 * F0 + tid];
  __syncthreads();
  {  // phase A: thread = output channel c of layer1
    const int c = tid;
    float w1r[F0];
#pragma unroll
    for (int k = 0; k < F0; ++k) w1r[k] = W1[k * F1 + c];
    const float bb = b1[c];
#pragma unroll
    for (int m = 0; m < MB; ++m) {
      float acc = bb;
#pragma unroll
      for (int k = 0; k < F0; ++k) acc += alds[m * F0 + k] * w1r[k];
      h1T[c][m] = fmaxf(acc, 0.f);
    }
  }
  __syncthreads();
  // phase B: thread computes 2 nodes x 4 cols; a-frag from LDS, W2 from global
  const int cg = tid & 31;  // 32 groups * 4 cols = 128
  const int mg = tid >> 5;  // 8 groups * 2 nodes = 16
  float a00 = 0.f, a01 = 0.f, a02 = 0.f, a03 = 0.f;
  float a10 = 0.f, a11 = 0.f, a12 = 0.f, a13 = 0.f;
#pragma unroll 4
  for (int k = 0; k < F1; ++k) {
    const float2 a = *(const float2*)&h1T[k][mg * 2];
    const float4 w = *(const float4*)&W2[k * F2 + cg * 4];
    a00 += a.x * w.x; a01 += a.x * w.y; a02 += a.x * w.z; a03 += a.x * w.w;
    a10 += a.y * w.x; a11 += a.y * w.y; a12 += a.y * w.z; a13 += a.y * w.w;
  }
  float4* o0 = (float4*)&t2[(size_t)(n0 + mg * 2) * F2 + cg * 4];
  float4* o1 = (float4*)&t2[(size_t)(n0 + mg * 2 + 1) * F2 + cg * 4];
  *o0 = make_float4(a00, a01, a02, a03);
  *o1 = make_float4(a10, a11, a12, a13);
}

// ---------- layer 2 agg + fused layer-3 transform ----------
// one wave per node: h2 = relu(A_hat t2 + b2) in regs; t3[n] = h2 . W3

__global__ __launch_bounds__(256) void k_agg2(
    const float* __restrict__ t2, const float* __restrict__ dinv,
    const int* __restrict__ rowp, const int* __restrict__ col,
    const float* __restrict__ enorm, const float* __restrict__ b2,
    const float* __restrict__ W3, float* __restrict__ t3) {
  const int n = (blockIdx.x * 256 + threadIdx.x) >> 6;
  const int lane = threadIdx.x & 63;
  if (n >= NN) return;
  const int jb = rowp[n], je = rowp[n + 1];
  const int fx = lane * 2;
  float ax = 0.f, ay = 0.f;
  for (int j = jb; j < je; ++j) {
    const int s = col[j];
    const float w = enorm[j];
    const float2 v = *(const float2*)&t2[(size_t)s * F2 + fx];
    ax += v.x * w;
    ay += v.y * w;
  }
  const float di = dinv[n];
  const float dw = di * di;
  const float2 vs = *(const float2*)&t2[(size_t)n * F2 + fx];
  ax += vs.x * dw;
  ay += vs.y * dw;
  ax = fmaxf(ax + b2[fx], 0.f);
  ay = fmaxf(ay + b2[fx + 1], 0.f);
  float p = ax * W3[fx] + ay * W3[fx + 1];
#pragma unroll
  for (int off = 32; off > 0; off >>= 1) p += __shfl_down(p, off);
  if (lane == 0) t3[n] = p;
}

// ---------- layer 3 scalar aggregation ----------

__global__ void k_agg3(const float* __restrict__ t3, const float* __restrict__ dinv,
                       const int* __restrict__ rowp, const int* __restrict__ col,
                       const float* __restrict__ enorm, const float* __restrict__ b3,
                       float* __restrict__ out) {
  int n = blockIdx.x * 256 + threadIdx.x;
  if (n >= NN) return;
  int jb = rowp[n], je = rowp[n + 1];
  float acc = 0.f;
  for (int j = jb; j < je; ++j) acc += t3[col[j]] * enorm[j];
  float di = dinv[n];
  out[n] = acc + t3[n] * di * di + b3[0];
}

extern "C" void kernel_launch(void* const* d_in, const int* in_sizes, int n_in,
                              void* d_out, int out_size, void* d_ws, size_t ws_size,
                              hipStream_t stream) {
  const float* x = (const float*)d_in[0];
  const int* ei = (const int*)d_in[1];
  const int* srcv = ei;           // edge_index[0]
  const int* dstv = ei + NE;      // edge_index[1]
  const float* W1 = (const float*)d_in[2];
  const float* b1 = (const float*)d_in[3];
  const float* W2 = (const float*)d_in[4];
  const float* b2 = (const float*)d_in[5];
  const float* W3 = (const float*)d_in[6];
  const float* b3 = (const float*)d_in[7];
  float* out = (float*)d_out;

  char* w = (char*)d_ws;
  auto alloc = [&](size_t bytes) -> void* {
    void* p = (void*)w;
    w += (bytes + 255) & ~(size_t)255;
    return p;
  };
  float* deg   = (float*)alloc(NN * 4);        // becomes dinv after k_scan
  int*   cursor= (int*)  alloc(NN * 4);
  int*   rowp  = (int*)  alloc((NN + 1) * 4);
  int*   col   = (int*)  alloc(NE * 4);
  float* enorm = (float*)alloc(NE * 4);
  float* a1    = (float*)alloc((size_t)NN * F0 * 4);
  float* t2    = (float*)alloc((size_t)NN * F2 * 4);
  float* t3    = (float*)alloc(NN * 4);

  k_init<<<(NN + 255) / 256, 256, 0, stream>>>(deg, cursor);
  k_count<<<(NE + 255) / 256, 256, 0, stream>>>(dstv, deg);
  k_scan<<<1, 1024, 0, stream>>>(deg, rowp);
  k_fill<<<(NE + 255) / 256, 256, 0, stream>>>(srcv, dstv, deg, rowp, cursor, col, enorm);
  k_aggx<<<(NN * 16 + 255) / 256, 256, 0, stream>>>(x, deg, rowp, col, enorm, a1);
  k_gemm12<<<NN / MB, 256, 0, stream>>>(a1, W1, b1, W2, t2);
  k_agg2<<<(NN + 3) / 4, 256, 0, stream>>>(t2, deg, rowp, col, enorm, b2, W3, t3);
  k_agg3<<<(NN + 255) / 256, 256, 0, stream>>>(t3, deg, rowp, col, enorm, b3, out);
}

// Round 2
// 218.412 us; speedup vs baseline: 1.1374x; 1.1374x over previous
//
#include <hip/hip_runtime.h>

// 3-layer GCN on MI355X. A_hat(xW) == (A_hat x)W: aggregate in the smaller dim.
// CSR-by-dst rebuilt on device every call (ws is re-poisoned between replays).

constexpr int NN = 20000;   // nodes
constexpr int NE = 320000;  // edges
constexpr int F0 = 10;      // input feats
constexpr int F1 = 256;     // layer1 out
constexpr int F2 = 128;     // layer2 out
constexpr int MB = 16;      // nodes per block in fused gemm12

// ---------- graph build ----------

__global__ void k_init(float* deg, int* cursor) {
  int i = blockIdx.x * 256 + threadIdx.x;
  if (i < NN) { deg[i] = 1.0f; cursor[i] = 0; }  // self-loop counts as 1
}

__global__ void k_count(const int* __restrict__ dst, float* deg) {
  int e = blockIdx.x * 256 + threadIdx.x;
  if (e < NE) atomicAdd(&deg[dst[e]], 1.0f);
}

// single block: exclusive-prefix of in-edge counts (deg-1) -> rowp, deg -> rsqrt(deg)
__global__ void k_scan(float* deg, int* rowp) {
  __shared__ int part[1024];
  const int t = threadIdx.x;
  const int CH = (NN + 1023) / 1024;  // 20
  const int base = t * CH;
  const int end = min(base + CH, NN);
  int s = 0;
  for (int i = base; i < end; ++i) s += (int)deg[i] - 1;
  part[t] = s;
  __syncthreads();
  for (int off = 1; off < 1024; off <<= 1) {
    int v = (t >= off) ? part[t - off] : 0;
    __syncthreads();
    part[t] += v;
    __syncthreads();
  }
  int run = part[t] - s;  // exclusive prefix
  for (int i = base; i < end; ++i) {
    float d = deg[i];
    rowp[i] = run;
    run += (int)d - 1;
    deg[i] = rsqrtf(d);  // deg >= 1 always
  }
  if (t == 0) rowp[NN] = NE;
}

__global__ void k_fill(const int* __restrict__ src, const int* __restrict__ dst,
                       const float* __restrict__ dinv, const int* __restrict__ rowp,
                       int* cursor, int* __restrict__ col, float* __restrict__ enorm) {
  int e = blockIdx.x * 256 + threadIdx.x;
  if (e < NE) {
    int d = dst[e], s = src[e];
    int pos = rowp[d] + atomicAdd(&cursor[d], 1);
    col[pos] = s;
    enorm[pos] = dinv[s] * dinv[d];
  }
}

// ---------- layer 1: a1 = A_hat x  (10 feats), 16 lanes per node ----------

__global__ void k_aggx(const float* __restrict__ x, const float* __restrict__ dinv,
                       const int* __restrict__ rowp, const int* __restrict__ col,
                       const float* __restrict__ enorm, float* __restrict__ a1) {
  int gid = blockIdx.x * 256 + threadIdx.x;
  int n = gid >> 4;
  int f = gid & 15;
  if (n >= NN || f >= F0) return;
  int jb = rowp[n], je = rowp[n + 1];
  float acc = 0.f;
  int j = jb;
  for (; j + 1 < je; j += 2) {
    int s0 = col[j], s1 = col[j + 1];
    float w0 = enorm[j], w1 = enorm[j + 1];
    acc += x[s0 * F0 + f] * w0 + x[s1 * F0 + f] * w1;
  }
  if (j < je) acc += x[col[j] * F0 + f] * enorm[j];
  float di = dinv[n];
  acc += x[n * F0 + f] * di * di;
  a1[n * F0 + f] = acc;
}

// ---------- fused: h1 = relu(a1 W1 + b1) in LDS; t2 = h1 W2 (W2 LDS-staged) ----

__global__ __launch_bounds__(256) void k_gemm12(
    const float* __restrict__ a1, const float* __restrict__ W1,
    const float* __restrict__ b1, const float* __restrict__ W2,
    float* __restrict__ t2) {
  __shared__ float alds[MB * F0];      // 640 B
  __shared__ float h1[MB][F1 + 4];     // 16.6 KB, [node][channel], stride 260
  __shared__ float w2lds[32][F2];      // 16 KB chunk of W2
  const int tid = threadIdx.x;
  const int n0 = blockIdx.x * MB;
  if (tid < MB * F0) alds[tid] = a1[n0 * F0 + tid];
  __syncthreads();
  {  // phase A: thread = layer-1 output channel c; writes h1[m][c] (stride-1 in c,
     // conflict-free vs R1's h1T[c][m] which had 480K bank conflicts)
    const int c = tid;
    float w1r[F0];
#pragma unroll
    for (int k = 0; k < F0; ++k) w1r[k] = W1[k * F1 + c];
    const float bb = b1[c];
#pragma unroll
    for (int m = 0; m < MB; ++m) {
      float acc = bb;
#pragma unroll
      for (int k = 0; k < F0; ++k) acc += alds[m * F0 + k] * w1r[k];
      h1[m][c] = fmaxf(acc, 0.f);
    }
  }
  // phase B: 2 nodes x 4 cols per thread; W2 staged through LDS in 32-row chunks
  // so the inner loop never touches L2 (R1 was latency-bound on L2 W2 reads).
  const int cg = tid & 31;  // 32 col-groups * 4 cols = 128
  const int mg = tid >> 5;  // 8 node-groups * 2 nodes = 16
  const int m0 = mg * 2;
  float a00 = 0.f, a01 = 0.f, a02 = 0.f, a03 = 0.f;
  float a10 = 0.f, a11 = 0.f, a12 = 0.f, a13 = 0.f;
  for (int kc = 0; kc < F1 / 32; ++kc) {
    __syncthreads();  // previous chunk fully consumed (also covers phase-A h1)
#pragma unroll
    for (int i = tid; i < 32 * 32; i += 256) {
      int r = i >> 5, q = i & 31;
      *(float4*)&w2lds[r][q * 4] = *(const float4*)&W2[(kc * 32 + r) * F2 + q * 4];
    }
    __syncthreads();
#pragma unroll 8
    for (int kk = 0; kk < 32; ++kk) {
      const int k = kc * 32 + kk;
      const float ax = h1[m0][k];
      const float ay = h1[m0 + 1][k];
      const float4 w = *(const float4*)&w2lds[kk][cg * 4];
      a00 += ax * w.x; a01 += ax * w.y; a02 += ax * w.z; a03 += ax * w.w;
      a10 += ay * w.x; a11 += ay * w.y; a12 += ay * w.z; a13 += ay * w.w;
    }
  }
  float4* o0 = (float4*)&t2[(size_t)(n0 + m0) * F2 + cg * 4];
  float4* o1 = (float4*)&t2[(size_t)(n0 + m0 + 1) * F2 + cg * 4];
  *o0 = make_float4(a00, a01, a02, a03);
  *o1 = make_float4(a10, a11, a12, a13);
}

// ---------- layer 2 agg + fused layer-3 transform ----------
// one wave per node: h2 = relu(A_hat t2 + b2) in regs; t3[n] = h2 . W3

__global__ __launch_bounds__(256) void k_agg2(
    const float* __restrict__ t2, const float* __restrict__ dinv,
    const int* __restrict__ rowp, const int* __restrict__ col,
    const float* __restrict__ enorm, const float* __restrict__ b2,
    const float* __restrict__ W3, float* __restrict__ t3) {
  // n is wave-uniform: force scalarization so col/enorm become s_loads
  const int n = __builtin_amdgcn_readfirstlane((blockIdx.x * 256 + threadIdx.x) >> 6);
  const int lane = threadIdx.x & 63;
  if (n >= NN) return;
  const int jb = rowp[n], je = rowp[n + 1];
  const int fx = lane * 2;
  float ax = 0.f, ay = 0.f;
  int j = jb;
  for (; j + 1 < je; j += 2) {  // 2 gathers in flight
    const int s0 = col[j], s1 = col[j + 1];
    const float w0 = enorm[j], w1 = enorm[j + 1];
    const float2 v0 = *(const float2*)&t2[(size_t)s0 * F2 + fx];
    const float2 v1 = *(const float2*)&t2[(size_t)s1 * F2 + fx];
    ax += v0.x * w0 + v1.x * w1;
    ay += v0.y * w0 + v1.y * w1;
  }
  if (j < je) {
    const int s = col[j];
    const float w = enorm[j];
    const float2 v = *(const float2*)&t2[(size_t)s * F2 + fx];
    ax += v.x * w;
    ay += v.y * w;
  }
  const float di = dinv[n];
  const float dw = di * di;
  const float2 vs = *(const float2*)&t2[(size_t)n * F2 + fx];
  ax += vs.x * dw;
  ay += vs.y * dw;
  ax = fmaxf(ax + b2[fx], 0.f);
  ay = fmaxf(ay + b2[fx + 1], 0.f);
  float p = ax * W3[fx] + ay * W3[fx + 1];
#pragma unroll
  for (int off = 32; off > 0; off >>= 1) p += __shfl_down(p, off);
  if (lane == 0) t3[n] = p;
}

// ---------- layer 3 scalar aggregation ----------

__global__ void k_agg3(const float* __restrict__ t3, const float* __restrict__ dinv,
                       const int* __restrict__ rowp, const int* __restrict__ col,
                       const float* __restrict__ enorm, const float* __restrict__ b3,
                       float* __restrict__ out) {
  int n = blockIdx.x * 256 + threadIdx.x;
  if (n >= NN) return;
  int jb = rowp[n], je = rowp[n + 1];
  float acc = 0.f;
  int j = jb;
  for (; j + 1 < je; j += 2)
    acc += t3[col[j]] * enorm[j] + t3[col[j + 1]] * enorm[j + 1];
  if (j < je) acc += t3[col[j]] * enorm[j];
  float di = dinv[n];
  out[n] = acc + t3[n] * di * di + b3[0];
}

extern "C" void kernel_launch(void* const* d_in, const int* in_sizes, int n_in,
                              void* d_out, int out_size, void* d_ws, size_t ws_size,
                              hipStream_t stream) {
  const float* x = (const float*)d_in[0];
  const int* ei = (const int*)d_in[1];
  const int* srcv = ei;           // edge_index[0]
  const int* dstv = ei + NE;      // edge_index[1]
  const float* W1 = (const float*)d_in[2];
  const float* b1 = (const float*)d_in[3];
  const float* W2 = (const float*)d_in[4];
  const float* b2 = (const float*)d_in[5];
  const float* W3 = (const float*)d_in[6];
  const float* b3 = (const float*)d_in[7];
  float* out = (float*)d_out;

  char* w = (char*)d_ws;
  auto alloc = [&](size_t bytes) -> void* {
    void* p = (void*)w;
    w += (bytes + 255) & ~(size_t)255;
    return p;
  };
  float* deg   = (float*)alloc(NN * 4);        // becomes dinv after k_scan
  int*   cursor= (int*)  alloc(NN * 4);
  int*   rowp  = (int*)  alloc((NN + 1) * 4);
  int*   col   = (int*)  alloc(NE * 4);
  float* enorm = (float*)alloc(NE * 4);
  float* a1    = (float*)alloc((size_t)NN * F0 * 4);
  float* t2    = (float*)alloc((size_t)NN * F2 * 4);
  float* t3    = (float*)alloc(NN * 4);

  k_init<<<(NN + 255) / 256, 256, 0, stream>>>(deg, cursor);
  k_count<<<(NE + 255) / 256, 256, 0, stream>>>(dstv, deg);
  k_scan<<<1, 1024, 0, stream>>>(deg, rowp);
  k_fill<<<(NE + 255) / 256, 256, 0, stream>>>(srcv, dstv, deg, rowp, cursor, col, enorm);
  k_aggx<<<(NN * 16 + 255) / 256, 256, 0, stream>>>(x, deg, rowp, col, enorm, a1);
  k_gemm12<<<NN / MB, 256, 0, stream>>>(a1, W1, b1, W2, t2);
  k_agg2<<<(NN + 3) / 4, 256, 0, stream>>>(t2, deg, rowp, col, enorm, b2, W3, t3);
  k_agg3<<<(NN + 255) / 256, 256, 0, stream>>>(t3, deg, rowp, col, enorm, b3, out);
}